// Round 10
// baseline (314.805 us; speedup 1.0000x reference)
//
#include <hip/hip_runtime.h>
#include <hip/hip_bf16.h>
#include <math.h>

// ImageTokenization: conv3x3(64->64)+BN+GELU -> patches(masked) -> proj GEMM(2304->768)+GELU
// Inputs fp32, outputs fp32; compute in bf16 MFMA (tolerance 8*2^-8).
// d_out (fp32) = [tokens 8192x768][patches 8192x2304].

typedef unsigned short u16;
typedef __bf16 bf16x8 __attribute__((ext_vector_type(8)));
typedef float f32x4 __attribute__((ext_vector_type(4)));

#define NFRM 32
#define CH 64
#define HW 96
#define HWP 98
#define KP 2304
#define DIMN 768
#define MTOK 8192
#define TOKN (MTOK * DIMN)          // 6,291,456 floats
#define NPAT (MTOK * KP)            // 18,874,368 floats
// ws layout (u16 units): [xhwc | bp | pw | abf(optional, ws-size-checked)]
#define XHWC_ELEMS ((size_t)NFRM * HWP * HWP * CH)   // 19,668,992
#define BP_OFF XHWC_ELEMS
#define PW_OFF (BP_OFF + 36864)
#define ABF_OFF (PW_OFF + 1769472)                   // 21,475,328
#define WS_NEED_FUSED (((size_t)ABF_OFF + (size_t)NPAT) * 2)  // bytes
#define BSTR 200                    // B LDS row stride (u16): 192 data + 8 pad

static __device__ __forceinline__ u16 f2b(float f) {
  unsigned u = __builtin_bit_cast(unsigned, f);
  u += 0x7fffu + ((u >> 16) & 1u);
  return (u16)(u >> 16);
}
static __device__ __forceinline__ float gelu_f(float x) {
  return 0.5f * x * (1.0f + erff(x * 0.7071067811865476f));
}

typedef __attribute__((address_space(3))) unsigned int lds_uint;
typedef __attribute__((address_space(1))) const unsigned int g_uint;
static __device__ __forceinline__ void gload16(const u16* g, u16* s) {
  // wave-uniform LDS base; HW writes base + lane*16; global src is per-lane.
  __builtin_amdgcn_global_load_lds((g_uint*)g, (lds_uint*)s, 16, 0, 0);
}

// -------- kernel 1: x[32][64][96][96] fp32 -> xhwc[32][98][98][64] bf16 ----
// Halo zeroing FUSED (replaces k_halo): every block zeroes col 0/97 of its row;
// h==0 block zeroes row 0; h==95 block zeroes row 97. Independent writes, no sync.
__global__ __launch_bounds__(256) void k_transpose(const float* __restrict__ x,
                                                   u16* __restrict__ xhwc) {
  __shared__ u16 tile[96 * 66];  // [w][ci], stride 66 breaks bank collisions
  const int f = blockIdx.x / 96, h = blockIdx.x % 96;
  const int t = threadIdx.x;
  const float* xp = x + (size_t)f * CH * HW * HW + (size_t)h * HW;
#pragma unroll
  for (int k = 0; k < 6; ++k) {
    int e = (k * 256 + t) * 4;
    int ci = e / 96, w = e % 96;
    float4 v = *(const float4*)(xp + (size_t)ci * (HW * HW) + w);
    tile[(w + 0) * 66 + ci] = f2b(v.x);
    tile[(w + 1) * 66 + ci] = f2b(v.y);
    tile[(w + 2) * 66 + ci] = f2b(v.z);
    tile[(w + 3) * 66 + ci] = f2b(v.w);
  }
  __syncthreads();
  u16* frm = xhwc + (size_t)f * HWP * HWP * CH;
  u16* op = frm + ((size_t)(h + 1) * HWP + 1) * CH;
#pragma unroll
  for (int k = 0; k < 12; ++k) {
    int e2 = (k * 256 + t) * 2;
    int w = e2 >> 6, ci = e2 & 63;
    *(unsigned*)(op + e2) = *(const unsigned*)(&tile[w * 66 + ci]);
  }
  // ---- halo zeroing (fused) ----
  const uint4 z = (uint4){0, 0, 0, 0};
  if (t < 16) {                          // col 0 and col 97 of row h+1
    const int col = (t < 8) ? 0 : 97;
    const int g = t & 7;
    *(uint4*)&frm[((size_t)(h + 1) * HWP + col) * CH + g * 8] = z;
  }
  if (h == 0) {                          // row 0: 98 px x 64 ch = 784 uint4
    for (int i = t; i < 784; i += 256) *(uint4*)&frm[(size_t)i * 8] = z;
  }
  if (h == 95) {                         // row 97
    u16* r97 = frm + (size_t)97 * HWP * CH;
    for (int i = t; i < 784; i += 256) *(uint4*)&r97[(size_t)i * 8] = z;
  }
}

// -------- kernel 2: merged weight prep (was k_bpack + k_pw; saves a launch) --------
// blocks 0..143: conv_w[co][ci][3][3] fp32 -> bp[co][tap*64+ci] bf16 (36,864 elems)
// blocks 144..1871: proj_w fp32 -> pw bf16 (1,769,472 elems, x4 vectorized)
__global__ __launch_bounds__(256) void k_prep(const float* __restrict__ w,
                                              const float* __restrict__ pwsrc,
                                              u16* __restrict__ bp,
                                              u16* __restrict__ pwd) {
  const int b = blockIdx.x;
  if (b < 144) {
    int e = b * 256 + threadIdx.x;  // < 36864
    int co = e / 576, r = e - co * 576, tap = r >> 6, ci = r & 63;
    bp[e] = f2b(w[(co * 64 + ci) * 9 + tap]);
  } else {
    int e = ((b - 144) * 256 + threadIdx.x) * 4;  // < 1,769,472
    float4 v = *(const float4*)(pwsrc + e);
    ushort4 o;
    o.x = f2b(v.x); o.y = f2b(v.y); o.z = f2b(v.z); o.w = f2b(v.w);
    *(ushort4*)(pwd + e) = o;
  }
}

// -------- kernel 4: half-strip conv, 6 waves (3wm x 2wn). ----------
// Block = frame x 8 patches (6 rows x 48 cols). SAME memory structure as rounds 6/9
// (79us, clean traffic): A 51,200B staged once (gload_lds w=16, granule-swizzled);
// B in LDS 3-tap phases (thrash-immune; B-in-reg at 3blk/CU thrashes L2: r4/r7);
// no XCD swizzle (r4); separated branch-free store loops (r5).
// SINGLE k_conv change vs round 9: 384 threads (6 waves = 3wm x 2wn). Pixel-dim split
// keeps total A-LDS-reads UNCHANGED (each frag still read by 2 wn-waves — r8's 4-wn
// split doubled them and lost); waves/CU 8->12 for latency hiding. Per-output
// accumulation chain (tap 0..8, ks 0..1; identical operand bytes) BIT-IDENTICAL.
__global__ __launch_bounds__(384, 3) void k_conv(
    const u16* __restrict__ xhwc, const u16* __restrict__ bw,
    const float* __restrict__ cb, const float* __restrict__ gma,
    const float* __restrict__ bta, const float* __restrict__ mu,
    const float* __restrict__ var, const float* __restrict__ msk,
    float* __restrict__ pout, u16* __restrict__ abf) {
  __shared__ alignas(16) char SMEM[76800];
  u16* Asm = (u16*)SMEM;                 // [400 px][64 u16], granule-swizzled
  u16* Bsm = (u16*)(SMEM + 51200);       // [64 co][BSTR u16], 3 taps per phase
  float* Fsm = (float*)SMEM;             // epilogue: 18,432 floats (73,728B)

  const int bx = blockIdx.x;
  const int f = bx >> 5, rem = bx & 31, pr = rem >> 1, half = rem & 1;
  const int t = threadIdx.x, wv = t >> 6, l = t & 63, quad = l >> 4, lm = l & 15;
  const int wm = wv >> 1, wn = wv & 1;   // 3 M-waves x 2 N-waves

  // ---- stage A once: xhwc rows pr*6 .. +7, cols half*48 .. +49 (halo included) ----
  const u16* sbase = xhwc + (((size_t)f * HWP + pr * 6) * HWP + half * 48) * CH;
  const int pc = l >> 3;                 // pixel-in-chunk 0..7  (== p&7)
  const int gsw = (l & 7) ^ pc;          // source granule for dest slot (l&7)
  for (int c = wv; c < 50; c += 6) {
    const int p = c * 8 + pc;            // strip pixel 0..399
    const int row = p / 50, ac = p - row * 50;
    gload16(sbase + ((size_t)row * HWP + ac) * CH + gsw * 8, Asm + c * 512);
  }

  int pb[6];
#pragma unroll
  for (int mf = 0; mf < 6; ++mf) {       // per-frag pixel base (strip = [6 rows][48 cols])
    const int i16 = wm * 6 + mf;         // 16-px run; 3 runs per row; 18 runs / 3 wm
    pb[mf] = (i16 / 3) * 50 + (i16 % 3) * 16 + lm;
  }
  f32x4 acc[6][2];
#pragma unroll
  for (int mf = 0; mf < 6; ++mf) {
    acc[mf][0] = (f32x4){0.f, 0.f, 0.f, 0.f};
    acc[mf][1] = (f32x4){0.f, 0.f, 0.f, 0.f};
  }

  // ---- 3 phases: taps {0,1,2},{3,4,5},{6,7,8}; di = ph, dj = tp ----
#pragma unroll
  for (int ph = 0; ph < 3; ++ph) {
    if (ph > 0) __syncthreads();         // all Bsm reads of previous phase done
    for (int e = t; e < 1536; e += 384) {
      const int co = e / 24, kk = e - co * 24;
      *(uint4*)&Bsm[co * BSTR + kk * 8] =
          *(const uint4*)&bw[co * 576 + ph * 192 + kk * 8];
    }
    __syncthreads();                     // B ready (ph 0: also drains A gload_lds vmcnt)
#pragma unroll
    for (int tp = 0; tp < 3; ++tp) {
      const int di = ph, dj = tp;        // tap = 3*ph + tp
#pragma unroll
      for (int ks = 0; ks < 2; ++ks) {
        const int kq = ks * 4 + quad;
        const bf16x8 b0 = *(const bf16x8*)&Bsm[(wn * 32 + lm) * BSTR + tp * 64 + ks * 32 + quad * 8];
        const bf16x8 b1 = *(const bf16x8*)&Bsm[(wn * 32 + 16 + lm) * BSTR + tp * 64 + ks * 32 + quad * 8];
#pragma unroll
        for (int mf = 0; mf < 6; ++mf) {
          const int p = pb[mf] + di * 50 + dj;
          const bf16x8 a = *(const bf16x8*)&Asm[p * 64 + ((kq ^ (p & 7)) << 3)];
          acc[mf][0] = __builtin_amdgcn_mfma_f32_16x16x32_bf16(a, b0, acc[mf][0], 0, 0, 0);
          acc[mf][1] = __builtin_amdgcn_mfma_f32_16x16x32_bf16(a, b1, acc[mf][1], 0, 0, 0);
        }
      }
    }
  }

  // ---- epilogue: BN + GELU + mask -> LDS (pout layout) -> coalesced stores ----
  __syncthreads();                       // all Asm/Bsm reads done; reuse LDS as float buffer
#pragma unroll
  for (int nf = 0; nf < 2; ++nf) {
    const int co = wn * 32 + nf * 16 + lm;   // C/D col = lane&15
    const float scv = gma[co] * rsqrtf(var[co] + 1e-5f);
    const float b2v = (cb[co] - mu[co]) * scv + bta[co];
#pragma unroll
    for (int mf = 0; mf < 6; ++mf) {
#pragma unroll
      for (int rg = 0; rg < 4; ++rg) {
        const int sp = wm * 96 + mf * 16 + quad * 4 + rg;  // strip pixel (row = quad*4+rg)
        const int orow = sp / 48, oc = sp - orow * 48;
        const int nl = oc / 6, pj = oc - nl * 6;
        const int jj = orow * 6 + pj;
        float v = acc[mf][nf][rg] * scv + b2v;
        v = gelu_f(v) * msk[jj];
        Fsm[nl * 2304 + co * 36 + jj] = v;
      }
    }
  }
  __syncthreads();
  const size_t brow = (size_t)(f * 256 + pr * 16 + half * 8) * KP;
  float* pbase = pout + brow;
  // loop 1: pout, branch-free (compiler batches ds_reads)
#pragma unroll
  for (int k = 0; k < 12; ++k) {
    const int li = t + k * 384;          // 4,608 float4 per block, dense
    *(float4*)&pbase[li * 4] = *(const float4*)&Fsm[li * 4];
  }
  // loop 2: bf16 abf, single uniform guard, branch-free body
  if (abf) {
    u16* adst = abf + brow;
#pragma unroll
    for (int k = 0; k < 12; ++k) {
      const int li = t + k * 384;
      const float4 w = *(const float4*)&Fsm[li * 4];
      ushort4 o;
      o.x = f2b(w.x); o.y = f2b(w.y); o.z = f2b(w.z); o.w = f2b(w.w);
      *(ushort4*)&adst[li * 4] = o;
    }
  }
}

// -------- kernel 5 (fallback only): patches fp32 -> A bf16 (into dead xhwc) --------
__global__ __launch_bounds__(256) void k_cvt(const float* __restrict__ pat,
                                             u16* __restrict__ abf) {
  int e = (blockIdx.x * 256 + threadIdx.x) * 4;  // < 18,874,368
  float4 v = *(const float4*)(pat + e);
  ushort4 o;
  o.x = f2b(v.x); o.y = f2b(v.y); o.z = f2b(v.z); o.w = f2b(v.w);
  *(ushort4*)(abf + e) = o;
}

// -------- kernel 6: tokens = gelu(A @ proj_w^T + proj_b), fp32 out (round-9, UNCHANGED) ----
// M=8192 K=2304 N=768; BM=128 BN=64 BK=128 (18 K-steps, 48KB LDS, 3 blocks/CU);
// gload_lds w=16 + 16-slot XOR granule swizzle both sides; bijective XCD-chunk swizzle
// (768=8x96): one A-panel's 12 bn-blocks stay on one XCD's L2. K ascending in 32-chunks
// -> accumulation chain identical to the BK=32 original.
__global__ __launch_bounds__(256) void k_gemm(const u16* __restrict__ A,
                                              const u16* __restrict__ Bt,
                                              const float* __restrict__ pb,
                                              float* __restrict__ out) {
  __shared__ alignas(16) u16 As[128 * 128];  // 32KB
  __shared__ alignas(16) u16 Bs[64 * 128];   // 16KB
  const int bid = blockIdx.x;
  const int logical = (bid & 7) * 96 + (bid >> 3);   // XCD-contiguous chunks
  const int bn = logical % 12, bm = logical / 12;
  const int m0 = bm * 128, n0 = bn * 64;
  const int t = threadIdx.x, wv = t >> 6, l = t & 63, quad = l >> 4, lm = l & 15;
  const int rl = l >> 4;                 // chunk-local row 0..3
  const int slot = l & 15;               // dest granule slot

  f32x4 acc[2][4];
#pragma unroll
  for (int s = 0; s < 2; ++s)
#pragma unroll
    for (int u = 0; u < 4; ++u) acc[s][u] = (f32x4){0.f, 0.f, 0.f, 0.f};

  for (int k0 = 0; k0 < KP; k0 += 128) {
    __syncthreads();
    // 48 chunks of 1KB (As 32 + Bs 16); chunk = 4 rows x 256B; wave-uniform dests.
    for (int c = wv; c < 48; c += 4) {
      if (c < 32) {
        const int row = c * 4 + rl;
        const int gsw2 = slot ^ (row & 15);          // pre-swizzled source granule
        gload16(A + (size_t)(m0 + row) * KP + k0 + gsw2 * 8, As + c * 512);
      } else {
        const int row = (c - 32) * 4 + rl;
        const int gsw2 = slot ^ (row & 15);
        gload16(Bt + (size_t)(n0 + row) * KP + k0 + gsw2 * 8, Bs + (c - 32) * 512);
      }
    }
    __syncthreads();                     // vmcnt(0) drain
#pragma unroll
    for (int ks = 0; ks < 4; ++ks) {
      const int gx = ((ks * 4 + quad) ^ lm) << 3;    // row&15 == lm for all reads
      const bf16x8 a0 = *(const bf16x8*)&As[(wv * 32 + lm) * 128 + gx];
      const bf16x8 a1 = *(const bf16x8*)&As[(wv * 32 + 16 + lm) * 128 + gx];
#pragma unroll
      for (int u = 0; u < 4; ++u) {
        const bf16x8 b = *(const bf16x8*)&Bs[(u * 16 + lm) * 128 + gx];
        acc[0][u] = __builtin_amdgcn_mfma_f32_16x16x32_bf16(a0, b, acc[0][u], 0, 0, 0);
        acc[1][u] = __builtin_amdgcn_mfma_f32_16x16x32_bf16(a1, b, acc[1][u], 0, 0, 0);
      }
    }
  }
#pragma unroll
  for (int u = 0; u < 4; ++u) {
    const int n = n0 + u * 16 + lm;
    const float bias = pb[n];
#pragma unroll
    for (int s = 0; s < 2; ++s) {
#pragma unroll
      for (int rg = 0; rg < 4; ++rg) {
        const int m = m0 + wv * 32 + s * 16 + quad * 4 + rg;
        out[(size_t)m * DIMN + n] = gelu_f(acc[s][u][rg] + bias);
      }
    }
  }
}

extern "C" void kernel_launch(void* const* d_in, const int* in_sizes, int n_in,
                              void* d_out, int out_size, void* d_ws, size_t ws_size,
                              hipStream_t stream) {
  const float* x = (const float*)d_in[0];
  const float* conv_w = (const float*)d_in[1];
  const float* conv_b = (const float*)d_in[2];
  const float* bn_gamma = (const float*)d_in[3];
  const float* bn_beta = (const float*)d_in[4];
  const float* bn_mean = (const float*)d_in[5];
  const float* bn_var = (const float*)d_in[6];
  const float* proj_w = (const float*)d_in[7];
  const float* proj_b = (const float*)d_in[8];
  const float* mask = (const float*)d_in[9];
  float* out = (float*)d_out;         // [tokens][patches], fp32
  float* patches = out + TOKN;
  u16* ws = (u16*)d_ws;
  u16* xhwc = ws;
  u16* bp = ws + BP_OFF;
  u16* pw = ws + PW_OFF;

  const bool fused = ws_size >= WS_NEED_FUSED;
  u16* abf = fused ? ws + ABF_OFF : (u16*)nullptr;

  k_transpose<<<NFRM * HW, 256, 0, stream>>>(x, xhwc);   // halo zeroing fused in
  k_prep<<<1872, 256, 0, stream>>>(conv_w, proj_w, bp, pw);
  k_conv<<<NFRM * 32, 384, 0, stream>>>(xhwc, bp, conv_b, bn_gamma, bn_beta,
                                        bn_mean, bn_var, mask, patches, abf);
  if (!fused) {
    k_cvt<<<18432, 256, 0, stream>>>(patches, xhwc);  // xhwc dead after k_conv
    abf = xhwc;
  }
  k_gemm<<<64 * 12, 256, 0, stream>>>(abf, pw, proj_b, out);
}

// Round 11
// 296.488 us; speedup vs baseline: 1.0618x; 1.0618x over previous
//
#include <hip/hip_runtime.h>
#include <hip/hip_bf16.h>
#include <math.h>

// ImageTokenization: conv3x3(64->64)+BN+GELU -> patches(masked) -> proj GEMM(2304->768)+GELU
// Inputs fp32, outputs fp32; compute in bf16 MFMA (tolerance 8*2^-8).
// d_out (fp32) = [tokens 8192x768][patches 8192x2304].

typedef unsigned short u16;
typedef __bf16 bf16x8 __attribute__((ext_vector_type(8)));
typedef float f32x4 __attribute__((ext_vector_type(4)));

#define NFRM 32
#define CH 64
#define HW 96
#define HWP 98
#define KP 2304
#define DIMN 768
#define MTOK 8192
#define TOKN (MTOK * DIMN)          // 6,291,456 floats
#define NPAT (MTOK * KP)            // 18,874,368 floats
// ws layout (u16 units): [xhwc | bp | pw | abf(optional, ws-size-checked)]
#define XHWC_ELEMS ((size_t)NFRM * HWP * HWP * CH)   // 19,668,992
#define BP_OFF XHWC_ELEMS
#define PW_OFF (BP_OFF + 36864)
#define ABF_OFF (PW_OFF + 1769472)                   // 21,475,328
#define WS_NEED_FUSED (((size_t)ABF_OFF + (size_t)NPAT) * 2)  // bytes
#define BSTR 200                    // B LDS row stride (u16): 192 data + 8 pad

static __device__ __forceinline__ u16 f2b(float f) {
  unsigned u = __builtin_bit_cast(unsigned, f);
  u += 0x7fffu + ((u >> 16) & 1u);
  return (u16)(u >> 16);
}
static __device__ __forceinline__ float gelu_f(float x) {
  return 0.5f * x * (1.0f + erff(x * 0.7071067811865476f));
}

typedef __attribute__((address_space(3))) unsigned int lds_uint;
typedef __attribute__((address_space(1))) const unsigned int g_uint;
static __device__ __forceinline__ void gload16(const u16* g, u16* s) {
  // wave-uniform LDS base; HW writes base + lane*16; global src is per-lane.
  __builtin_amdgcn_global_load_lds((g_uint*)g, (lds_uint*)s, 16, 0, 0);
}

// -------- kernel 1: x[32][64][96][96] fp32 -> xhwc[32][98][98][64] bf16 ----
// Halo zeroing FUSED (r10, kept): every block zeroes col 0/97 of its row;
// h==0 block zeroes row 0; h==95 block zeroes row 97. Independent writes, no sync.
__global__ __launch_bounds__(256) void k_transpose(const float* __restrict__ x,
                                                   u16* __restrict__ xhwc) {
  __shared__ u16 tile[96 * 66];  // [w][ci], stride 66 breaks bank collisions
  const int f = blockIdx.x / 96, h = blockIdx.x % 96;
  const int t = threadIdx.x;
  const float* xp = x + (size_t)f * CH * HW * HW + (size_t)h * HW;
#pragma unroll
  for (int k = 0; k < 6; ++k) {
    int e = (k * 256 + t) * 4;
    int ci = e / 96, w = e % 96;
    float4 v = *(const float4*)(xp + (size_t)ci * (HW * HW) + w);
    tile[(w + 0) * 66 + ci] = f2b(v.x);
    tile[(w + 1) * 66 + ci] = f2b(v.y);
    tile[(w + 2) * 66 + ci] = f2b(v.z);
    tile[(w + 3) * 66 + ci] = f2b(v.w);
  }
  __syncthreads();
  u16* frm = xhwc + (size_t)f * HWP * HWP * CH;
  u16* op = frm + ((size_t)(h + 1) * HWP + 1) * CH;
#pragma unroll
  for (int k = 0; k < 12; ++k) {
    int e2 = (k * 256 + t) * 2;
    int w = e2 >> 6, ci = e2 & 63;
    *(unsigned*)(op + e2) = *(const unsigned*)(&tile[w * 66 + ci]);
  }
  // ---- halo zeroing (fused) ----
  const uint4 z = (uint4){0, 0, 0, 0};
  if (t < 16) {                          // col 0 and col 97 of row h+1
    const int col = (t < 8) ? 0 : 97;
    const int g = t & 7;
    *(uint4*)&frm[((size_t)(h + 1) * HWP + col) * CH + g * 8] = z;
  }
  if (h == 0) {                          // row 0: 98 px x 64 ch = 784 uint4
    for (int i = t; i < 784; i += 256) *(uint4*)&frm[(size_t)i * 8] = z;
  }
  if (h == 95) {                         // row 97
    u16* r97 = frm + (size_t)97 * HWP * CH;
    for (int i = t; i < 784; i += 256) *(uint4*)&r97[(size_t)i * 8] = z;
  }
}

// -------- kernel 2: merged weight prep (r10, kept; was k_bpack + k_pw) --------
// blocks 0..143: conv_w[co][ci][3][3] fp32 -> bp[co][tap*64+ci] bf16 (36,864 elems)
// blocks 144..1871: proj_w fp32 -> pw bf16 (1,769,472 elems, x4 vectorized)
__global__ __launch_bounds__(256) void k_prep(const float* __restrict__ w,
                                              const float* __restrict__ pwsrc,
                                              u16* __restrict__ bp,
                                              u16* __restrict__ pwd) {
  const int b = blockIdx.x;
  if (b < 144) {
    int e = b * 256 + threadIdx.x;  // < 36864
    int co = e / 576, r = e - co * 576, tap = r >> 6, ci = r & 63;
    bp[e] = f2b(w[(co * 64 + ci) * 9 + tap]);
  } else {
    int e = ((b - 144) * 256 + threadIdx.x) * 4;  // < 1,769,472
    float4 v = *(const float4*)(pwsrc + e);
    ushort4 o;
    o.x = f2b(v.x); o.y = f2b(v.y); o.z = f2b(v.z); o.w = f2b(v.w);
    *(ushort4*)(pwd + e) = o;
  }
}

// -------- kernel 4: half-strip conv (round-9/6 proven version, 79us, EXACT revert). ----
// Block = frame x 8 patches (6 rows x 48 cols), 256 threads (4 waves = 2wm x 2wn).
// LOCAL OPTIMUM — all five structural variants lost: 512t/8w-grid-wide (r1), B-in-reg
// 3blk/CU (r4/r7: L2 thrash, FETCH 26.5->78-128MB), 8w co-split (r8: 2x A-LDS-reads),
// 6w pixel-split (r10: uneven SIMD mapping, occupancy DOWN). Also: no XCD swizzle (r4
// breaks producer->consumer L2 locality); separated branch-free store loops (r5:
// interleaved convert+store serialized the ds_read pipeline, 2x stall).
// A: 51,200B staged once (gload_lds w=16, granule-swizzled); B in LDS, 3-tap phases.
// Accumulation chain BIT-IDENTICAL to rounds 0-10.
__global__ __launch_bounds__(256, 2) void k_conv(
    const u16* __restrict__ xhwc, const u16* __restrict__ bw,
    const float* __restrict__ cb, const float* __restrict__ gma,
    const float* __restrict__ bta, const float* __restrict__ mu,
    const float* __restrict__ var, const float* __restrict__ msk,
    float* __restrict__ pout, u16* __restrict__ abf) {
  __shared__ alignas(16) char SMEM[76800];
  u16* Asm = (u16*)SMEM;                 // [400 px][64 u16], granule-swizzled
  u16* Bsm = (u16*)(SMEM + 51200);       // [64 co][BSTR u16], 3 taps per phase
  float* Fsm = (float*)SMEM;             // epilogue: 18,432 floats (73,728B)

  const int bx = blockIdx.x;
  const int f = bx >> 5, rem = bx & 31, pr = rem >> 1, half = rem & 1;
  const int t = threadIdx.x, wv = t >> 6, l = t & 63, quad = l >> 4, lm = l & 15;
  const int wm = wv >> 1, wn = wv & 1;

  // ---- stage A once: xhwc rows pr*6 .. +7, cols half*48 .. +49 (halo included) ----
  const u16* sbase = xhwc + (((size_t)f * HWP + pr * 6) * HWP + half * 48) * CH;
  const int pc = l >> 3;                 // pixel-in-chunk 0..7  (== p&7)
  const int gsw = (l & 7) ^ pc;          // source granule for dest slot (l&7)
  for (int c = wv; c < 50; c += 4) {
    const int p = c * 8 + pc;            // strip pixel 0..399
    const int row = p / 50, ac = p - row * 50;
    gload16(sbase + ((size_t)row * HWP + ac) * CH + gsw * 8, Asm + c * 512);
  }

  int pb[9];
#pragma unroll
  for (int mf = 0; mf < 9; ++mf) {       // per-frag pixel base (strip = [6 rows][48 cols])
    const int i16 = wm * 9 + mf;         // 16-px run; 3 runs per row
    pb[mf] = (i16 / 3) * 50 + (i16 % 3) * 16 + lm;
  }
  f32x4 acc[9][2];
#pragma unroll
  for (int mf = 0; mf < 9; ++mf) {
    acc[mf][0] = (f32x4){0.f, 0.f, 0.f, 0.f};
    acc[mf][1] = (f32x4){0.f, 0.f, 0.f, 0.f};
  }

  // ---- 3 phases: taps {0,1,2},{3,4,5},{6,7,8}; di = ph, dj = tp ----
#pragma unroll
  for (int ph = 0; ph < 3; ++ph) {
    if (ph > 0) __syncthreads();         // all Bsm reads of previous phase done
    for (int e = t; e < 1536; e += 256) {
      const int co = e / 24, kk = e - co * 24;
      *(uint4*)&Bsm[co * BSTR + kk * 8] =
          *(const uint4*)&bw[co * 576 + ph * 192 + kk * 8];
    }
    __syncthreads();                     // B ready (ph 0: also drains A gload_lds vmcnt)
#pragma unroll
    for (int tp = 0; tp < 3; ++tp) {
      const int di = ph, dj = tp;        // tap = 3*ph + tp
#pragma unroll
      for (int ks = 0; ks < 2; ++ks) {
        const int kq = ks * 4 + quad;
        const bf16x8 b0 = *(const bf16x8*)&Bsm[(wn * 32 + lm) * BSTR + tp * 64 + ks * 32 + quad * 8];
        const bf16x8 b1 = *(const bf16x8*)&Bsm[(wn * 32 + 16 + lm) * BSTR + tp * 64 + ks * 32 + quad * 8];
#pragma unroll
        for (int mf = 0; mf < 9; ++mf) {
          const int p = pb[mf] + di * 50 + dj;
          const bf16x8 a = *(const bf16x8*)&Asm[p * 64 + ((kq ^ (p & 7)) << 3)];
          acc[mf][0] = __builtin_amdgcn_mfma_f32_16x16x32_bf16(a, b0, acc[mf][0], 0, 0, 0);
          acc[mf][1] = __builtin_amdgcn_mfma_f32_16x16x32_bf16(a, b1, acc[mf][1], 0, 0, 0);
        }
      }
    }
  }

  // ---- epilogue: BN + GELU + mask -> LDS (pout layout) -> coalesced stores ----
  __syncthreads();                       // all Asm/Bsm reads done; reuse LDS as float buffer
#pragma unroll
  for (int nf = 0; nf < 2; ++nf) {
    const int co = wn * 32 + nf * 16 + lm;   // C/D col = lane&15
    const float scv = gma[co] * rsqrtf(var[co] + 1e-5f);
    const float b2v = (cb[co] - mu[co]) * scv + bta[co];
#pragma unroll
    for (int mf = 0; mf < 9; ++mf) {
#pragma unroll
      for (int rg = 0; rg < 4; ++rg) {
        const int sp = wm * 144 + mf * 16 + quad * 4 + rg;  // strip pixel (row = quad*4+rg)
        const int orow = sp / 48, oc = sp - orow * 48;
        const int nl = oc / 6, pj = oc - nl * 6;
        const int jj = orow * 6 + pj;
        float v = acc[mf][nf][rg] * scv + b2v;
        v = gelu_f(v) * msk[jj];
        Fsm[nl * 2304 + co * 36 + jj] = v;
      }
    }
  }
  __syncthreads();
  const size_t brow = (size_t)(f * 256 + pr * 16 + half * 8) * KP;
  float* pbase = pout + brow;
  // loop 1: pout, branch-free (compiler batches ds_reads)
#pragma unroll
  for (int k = 0; k < 18; ++k) {
    const int li = t + k * 256;          // 4,608 float4 per block, dense
    *(float4*)&pbase[li * 4] = *(const float4*)&Fsm[li * 4];
  }
  // loop 2: bf16 abf, single uniform guard, branch-free body
  if (abf) {
    u16* adst = abf + brow;
#pragma unroll
    for (int k = 0; k < 18; ++k) {
      const int li = t + k * 256;
      const float4 w = *(const float4*)&Fsm[li * 4];
      ushort4 o;
      o.x = f2b(w.x); o.y = f2b(w.y); o.z = f2b(w.z); o.w = f2b(w.w);
      *(ushort4*)&adst[li * 4] = o;
    }
  }
}

// -------- kernel 5 (fallback only): patches fp32 -> A bf16 (into dead xhwc) --------
__global__ __launch_bounds__(256) void k_cvt(const float* __restrict__ pat,
                                             u16* __restrict__ abf) {
  int e = (blockIdx.x * 256 + threadIdx.x) * 4;  // < 18,874,368
  float4 v = *(const float4*)(pat + e);
  ushort4 o;
  o.x = f2b(v.x); o.y = f2b(v.y); o.z = f2b(v.z); o.w = f2b(v.w);
  *(ushort4*)(abf + e) = o;
}

// -------- kernel 6: tokens = gelu(A @ proj_w^T + proj_b), fp32 out (round-9, UNCHANGED) ----
// M=8192 K=2304 N=768; BM=128 BN=64 BK=128 (18 K-steps, 48KB LDS, 3 blocks/CU);
// gload_lds w=16 + 16-slot XOR granule swizzle both sides; bijective XCD-chunk swizzle
// (768=8x96): one A-panel's 12 bn-blocks stay on one XCD's L2. K ascending in 32-chunks
// -> accumulation chain identical to the BK=32 original.
__global__ __launch_bounds__(256) void k_gemm(const u16* __restrict__ A,
                                              const u16* __restrict__ Bt,
                                              const float* __restrict__ pb,
                                              float* __restrict__ out) {
  __shared__ alignas(16) u16 As[128 * 128];  // 32KB
  __shared__ alignas(16) u16 Bs[64 * 128];   // 16KB
  const int bid = blockIdx.x;
  const int logical = (bid & 7) * 96 + (bid >> 3);   // XCD-contiguous chunks
  const int bn = logical % 12, bm = logical / 12;
  const int m0 = bm * 128, n0 = bn * 64;
  const int t = threadIdx.x, wv = t >> 6, l = t & 63, quad = l >> 4, lm = l & 15;
  const int rl = l >> 4;                 // chunk-local row 0..3
  const int slot = l & 15;               // dest granule slot

  f32x4 acc[2][4];
#pragma unroll
  for (int s = 0; s < 2; ++s)
#pragma unroll
    for (int u = 0; u < 4; ++u) acc[s][u] = (f32x4){0.f, 0.f, 0.f, 0.f};

  for (int k0 = 0; k0 < KP; k0 += 128) {
    __syncthreads();
    // 48 chunks of 1KB (As 32 + Bs 16); chunk = 4 rows x 256B; wave-uniform dests.
    for (int c = wv; c < 48; c += 4) {
      if (c < 32) {
        const int row = c * 4 + rl;
        const int gsw2 = slot ^ (row & 15);          // pre-swizzled source granule
        gload16(A + (size_t)(m0 + row) * KP + k0 + gsw2 * 8, As + c * 512);
      } else {
        const int row = (c - 32) * 4 + rl;
        const int gsw2 = slot ^ (row & 15);
        gload16(Bt + (size_t)(n0 + row) * KP + k0 + gsw2 * 8, Bs + (c - 32) * 512);
      }
    }
    __syncthreads();                     // vmcnt(0) drain
#pragma unroll
    for (int ks = 0; ks < 4; ++ks) {
      const int gx = ((ks * 4 + quad) ^ lm) << 3;    // row&15 == lm for all reads
      const bf16x8 a0 = *(const bf16x8*)&As[(wv * 32 + lm) * 128 + gx];
      const bf16x8 a1 = *(const bf16x8*)&As[(wv * 32 + 16 + lm) * 128 + gx];
#pragma unroll
      for (int u = 0; u < 4; ++u) {
        const bf16x8 b = *(const bf16x8*)&Bs[(u * 16 + lm) * 128 + gx];
        acc[0][u] = __builtin_amdgcn_mfma_f32_16x16x32_bf16(a0, b, acc[0][u], 0, 0, 0);
        acc[1][u] = __builtin_amdgcn_mfma_f32_16x16x32_bf16(a1, b, acc[1][u], 0, 0, 0);
      }
    }
  }
#pragma unroll
  for (int u = 0; u < 4; ++u) {
    const int n = n0 + u * 16 + lm;
    const float bias = pb[n];
#pragma unroll
    for (int s = 0; s < 2; ++s) {
#pragma unroll
      for (int rg = 0; rg < 4; ++rg) {
        const int m = m0 + wv * 32 + s * 16 + quad * 4 + rg;
        out[(size_t)m * DIMN + n] = gelu_f(acc[s][u][rg] + bias);
      }
    }
  }
}

extern "C" void kernel_launch(void* const* d_in, const int* in_sizes, int n_in,
                              void* d_out, int out_size, void* d_ws, size_t ws_size,
                              hipStream_t stream) {
  const float* x = (const float*)d_in[0];
  const float* conv_w = (const float*)d_in[1];
  const float* conv_b = (const float*)d_in[2];
  const float* bn_gamma = (const float*)d_in[3];
  const float* bn_beta = (const float*)d_in[4];
  const float* bn_mean = (const float*)d_in[5];
  const float* bn_var = (const float*)d_in[6];
  const float* proj_w = (const float*)d_in[7];
  const float* proj_b = (const float*)d_in[8];
  const float* mask = (const float*)d_in[9];
  float* out = (float*)d_out;         // [tokens][patches], fp32
  float* patches = out + TOKN;
  u16* ws = (u16*)d_ws;
  u16* xhwc = ws;
  u16* bp = ws + BP_OFF;
  u16* pw = ws + PW_OFF;

  const bool fused = ws_size >= WS_NEED_FUSED;
  u16* abf = fused ? ws + ABF_OFF : (u16*)nullptr;

  k_transpose<<<NFRM * HW, 256, 0, stream>>>(x, xhwc);   // halo zeroing fused in
  k_prep<<<1872, 256, 0, stream>>>(conv_w, proj_w, bp, pw);
  k_conv<<<NFRM * 32, 256, 0, stream>>>(xhwc, bp, conv_b, bn_gamma, bn_beta,
                                        bn_mean, bn_var, mask, patches, abf);
  if (!fused) {
    k_cvt<<<18432, 256, 0, stream>>>(patches, xhwc);  // xhwc dead after k_conv
    abf = xhwc;
  }
  k_gemm<<<64 * 12, 256, 0, stream>>>(abf, pw, proj_b, out);
}

// Round 12
// 296.475 us; speedup vs baseline: 1.0618x; 1.0000x over previous
//
#include <hip/hip_runtime.h>
#include <hip/hip_bf16.h>
#include <math.h>

// ImageTokenization: conv3x3(64->64)+BN+GELU -> patches(masked) -> proj GEMM(2304->768)+GELU
// Inputs fp32, outputs fp32; compute in bf16 MFMA (tolerance 8*2^-8).
// d_out (fp32) = [tokens 8192x768][patches 8192x2304].

typedef unsigned short u16;
typedef __bf16 bf16x8 __attribute__((ext_vector_type(8)));
typedef float f32x4 __attribute__((ext_vector_type(4)));

#define NFRM 32
#define CH 64
#define HW 96
#define HWP 98
#define KP 2304
#define DIMN 768
#define MTOK 8192
#define TOKN (MTOK * DIMN)          // 6,291,456 floats
#define NPAT (MTOK * KP)            // 18,874,368 floats
// ws layout (u16 units): [xhwc | bp | pw | abf(optional, ws-size-checked)]
#define XHWC_ELEMS ((size_t)NFRM * HWP * HWP * CH)   // 19,668,992
#define BP_OFF XHWC_ELEMS
#define PW_OFF (BP_OFF + 36864)
#define ABF_OFF (PW_OFF + 1769472)                   // 21,475,328
#define WS_NEED_FUSED (((size_t)ABF_OFF + (size_t)NPAT) * 2)  // bytes
#define BSTR 200                    // B LDS row stride (u16): 192 data + 8 pad

static __device__ __forceinline__ u16 f2b(float f) {
  unsigned u = __builtin_bit_cast(unsigned, f);
  u += 0x7fffu + ((u >> 16) & 1u);
  return (u16)(u >> 16);
}
static __device__ __forceinline__ float gelu_f(float x) {
  return 0.5f * x * (1.0f + erff(x * 0.7071067811865476f));
}

typedef __attribute__((address_space(3))) unsigned int lds_uint;
typedef __attribute__((address_space(1))) const unsigned int g_uint;
static __device__ __forceinline__ void gload16(const u16* g, u16* s) {
  // wave-uniform LDS base; HW writes base + lane*16; global src is per-lane.
  __builtin_amdgcn_global_load_lds((g_uint*)g, (lds_uint*)s, 16, 0, 0);
}

// -------- kernel 1: x[32][64][96][96] fp32 -> xhwc[32][98][98][64] bf16 ----
// Halo zeroing FUSED (r10, kept): every block zeroes col 0/97 of its row;
// h==0 block zeroes row 0; h==95 block zeroes row 97. Independent writes, no sync.
__global__ __launch_bounds__(256) void k_transpose(const float* __restrict__ x,
                                                   u16* __restrict__ xhwc) {
  __shared__ u16 tile[96 * 66];  // [w][ci], stride 66 breaks bank collisions
  const int f = blockIdx.x / 96, h = blockIdx.x % 96;
  const int t = threadIdx.x;
  const float* xp = x + (size_t)f * CH * HW * HW + (size_t)h * HW;
#pragma unroll
  for (int k = 0; k < 6; ++k) {
    int e = (k * 256 + t) * 4;
    int ci = e / 96, w = e % 96;
    float4 v = *(const float4*)(xp + (size_t)ci * (HW * HW) + w);
    tile[(w + 0) * 66 + ci] = f2b(v.x);
    tile[(w + 1) * 66 + ci] = f2b(v.y);
    tile[(w + 2) * 66 + ci] = f2b(v.z);
    tile[(w + 3) * 66 + ci] = f2b(v.w);
  }
  __syncthreads();
  u16* frm = xhwc + (size_t)f * HWP * HWP * CH;
  u16* op = frm + ((size_t)(h + 1) * HWP + 1) * CH;
#pragma unroll
  for (int k = 0; k < 12; ++k) {
    int e2 = (k * 256 + t) * 2;
    int w = e2 >> 6, ci = e2 & 63;
    *(unsigned*)(op + e2) = *(const unsigned*)(&tile[w * 66 + ci]);
  }
  // ---- halo zeroing (fused) ----
  const uint4 z = (uint4){0, 0, 0, 0};
  if (t < 16) {                          // col 0 and col 97 of row h+1
    const int col = (t < 8) ? 0 : 97;
    const int g = t & 7;
    *(uint4*)&frm[((size_t)(h + 1) * HWP + col) * CH + g * 8] = z;
  }
  if (h == 0) {                          // row 0: 98 px x 64 ch = 784 uint4
    for (int i = t; i < 784; i += 256) *(uint4*)&frm[(size_t)i * 8] = z;
  }
  if (h == 95) {                         // row 97
    u16* r97 = frm + (size_t)97 * HWP * CH;
    for (int i = t; i < 784; i += 256) *(uint4*)&r97[(size_t)i * 8] = z;
  }
}

// -------- kernel 2: merged weight prep (r10, kept; was k_bpack + k_pw) --------
// blocks 0..143: conv_w[co][ci][3][3] fp32 -> bp[co][tap*64+ci] bf16 (36,864 elems)
// blocks 144..1871: proj_w fp32 -> pw bf16 (1,769,472 elems, x4 vectorized)
__global__ __launch_bounds__(256) void k_prep(const float* __restrict__ w,
                                              const float* __restrict__ pwsrc,
                                              u16* __restrict__ bp,
                                              u16* __restrict__ pwd) {
  const int b = blockIdx.x;
  if (b < 144) {
    int e = b * 256 + threadIdx.x;  // < 36864
    int co = e / 576, r = e - co * 576, tap = r >> 6, ci = r & 63;
    bp[e] = f2b(w[(co * 64 + ci) * 9 + tap]);
  } else {
    int e = ((b - 144) * 256 + threadIdx.x) * 4;  // < 1,769,472
    float4 v = *(const float4*)(pwsrc + e);
    ushort4 o;
    o.x = f2b(v.x); o.y = f2b(v.y); o.z = f2b(v.z); o.w = f2b(v.w);
    *(ushort4*)(pwd + e) = o;
  }
}

// -------- kernel 4: half-strip conv (r9/6 structure; epilogue single-Fsm-read). ----
// Block = frame x 8 patches (6 rows x 48 cols), 256 threads (4 waves = 2wm x 2wn).
// LOCAL OPTIMUM — all five structural variants lost: 512t/8w-grid-wide (r1), B-in-reg
// 3blk/CU (r4/r7: L2 thrash, FETCH 26.5->78-128MB), 8w co-split (r8: 2x A-LDS-reads),
// 6w pixel-split (r10: uneven SIMD mapping, occupancy DOWN). Also: no XCD swizzle (r4
// breaks producer->consumer L2 locality); store loops must stay branch-free (r5).
// A: 51,200B staged once (gload_lds w=16, granule-swizzled); B in LDS, 3-tap phases.
// r12 change: epilogue reads Fsm ONCE into registers (2 batches of 9 float4, VGPR-safe),
// feeding both pout and abf store streams — halves epilogue LDS reads and removes the
// second read-latency chain (r6 read Fsm twice).
// Accumulation chain BIT-IDENTICAL to rounds 0-11.
__global__ __launch_bounds__(256, 2) void k_conv(
    const u16* __restrict__ xhwc, const u16* __restrict__ bw,
    const float* __restrict__ cb, const float* __restrict__ gma,
    const float* __restrict__ bta, const float* __restrict__ mu,
    const float* __restrict__ var, const float* __restrict__ msk,
    float* __restrict__ pout, u16* __restrict__ abf) {
  __shared__ alignas(16) char SMEM[76800];
  u16* Asm = (u16*)SMEM;                 // [400 px][64 u16], granule-swizzled
  u16* Bsm = (u16*)(SMEM + 51200);       // [64 co][BSTR u16], 3 taps per phase
  float* Fsm = (float*)SMEM;             // epilogue: 18,432 floats (73,728B)

  const int bx = blockIdx.x;
  const int f = bx >> 5, rem = bx & 31, pr = rem >> 1, half = rem & 1;
  const int t = threadIdx.x, wv = t >> 6, l = t & 63, quad = l >> 4, lm = l & 15;
  const int wm = wv >> 1, wn = wv & 1;

  // ---- stage A once: xhwc rows pr*6 .. +7, cols half*48 .. +49 (halo included) ----
  const u16* sbase = xhwc + (((size_t)f * HWP + pr * 6) * HWP + half * 48) * CH;
  const int pc = l >> 3;                 // pixel-in-chunk 0..7  (== p&7)
  const int gsw = (l & 7) ^ pc;          // source granule for dest slot (l&7)
  for (int c = wv; c < 50; c += 4) {
    const int p = c * 8 + pc;            // strip pixel 0..399
    const int row = p / 50, ac = p - row * 50;
    gload16(sbase + ((size_t)row * HWP + ac) * CH + gsw * 8, Asm + c * 512);
  }

  int pb[9];
#pragma unroll
  for (int mf = 0; mf < 9; ++mf) {       // per-frag pixel base (strip = [6 rows][48 cols])
    const int i16 = wm * 9 + mf;         // 16-px run; 3 runs per row
    pb[mf] = (i16 / 3) * 50 + (i16 % 3) * 16 + lm;
  }
  f32x4 acc[9][2];
#pragma unroll
  for (int mf = 0; mf < 9; ++mf) {
    acc[mf][0] = (f32x4){0.f, 0.f, 0.f, 0.f};
    acc[mf][1] = (f32x4){0.f, 0.f, 0.f, 0.f};
  }

  // ---- 3 phases: taps {0,1,2},{3,4,5},{6,7,8}; di = ph, dj = tp ----
#pragma unroll
  for (int ph = 0; ph < 3; ++ph) {
    if (ph > 0) __syncthreads();         // all Bsm reads of previous phase done
    for (int e = t; e < 1536; e += 256) {
      const int co = e / 24, kk = e - co * 24;
      *(uint4*)&Bsm[co * BSTR + kk * 8] =
          *(const uint4*)&bw[co * 576 + ph * 192 + kk * 8];
    }
    __syncthreads();                     // B ready (ph 0: also drains A gload_lds vmcnt)
#pragma unroll
    for (int tp = 0; tp < 3; ++tp) {
      const int di = ph, dj = tp;        // tap = 3*ph + tp
#pragma unroll
      for (int ks = 0; ks < 2; ++ks) {
        const int kq = ks * 4 + quad;
        const bf16x8 b0 = *(const bf16x8*)&Bsm[(wn * 32 + lm) * BSTR + tp * 64 + ks * 32 + quad * 8];
        const bf16x8 b1 = *(const bf16x8*)&Bsm[(wn * 32 + 16 + lm) * BSTR + tp * 64 + ks * 32 + quad * 8];
#pragma unroll
        for (int mf = 0; mf < 9; ++mf) {
          const int p = pb[mf] + di * 50 + dj;
          const bf16x8 a = *(const bf16x8*)&Asm[p * 64 + ((kq ^ (p & 7)) << 3)];
          acc[mf][0] = __builtin_amdgcn_mfma_f32_16x16x32_bf16(a, b0, acc[mf][0], 0, 0, 0);
          acc[mf][1] = __builtin_amdgcn_mfma_f32_16x16x32_bf16(a, b1, acc[mf][1], 0, 0, 0);
        }
      }
    }
  }

  // ---- epilogue: BN + GELU + mask -> LDS (pout layout) -> coalesced stores ----
  __syncthreads();                       // all Asm/Bsm reads done; reuse LDS as float buffer
#pragma unroll
  for (int nf = 0; nf < 2; ++nf) {
    const int co = wn * 32 + nf * 16 + lm;   // C/D col = lane&15
    const float scv = gma[co] * rsqrtf(var[co] + 1e-5f);
    const float b2v = (cb[co] - mu[co]) * scv + bta[co];
#pragma unroll
    for (int mf = 0; mf < 9; ++mf) {
#pragma unroll
      for (int rg = 0; rg < 4; ++rg) {
        const int sp = wm * 144 + mf * 16 + quad * 4 + rg;  // strip pixel (row = quad*4+rg)
        const int orow = sp / 48, oc = sp - orow * 48;
        const int nl = oc / 6, pj = oc - nl * 6;
        const int jj = orow * 6 + pj;
        float v = acc[mf][nf][rg] * scv + b2v;
        v = gelu_f(v) * msk[jj];
        Fsm[nl * 2304 + co * 36 + jj] = v;
      }
    }
  }
  __syncthreads();
  const size_t brow = (size_t)(f * 256 + pr * 16 + half * 8) * KP;
  float* pbase = pout + brow;
  u16* adst = abf ? abf + brow : (u16*)nullptr;
  // single Fsm read -> registers -> two batched branch-free store streams
#pragma unroll
  for (int half9 = 0; half9 < 2; ++half9) {
    float4 w[9];
#pragma unroll
    for (int k = 0; k < 9; ++k)
      w[k] = *(const float4*)&Fsm[(t + (half9 * 9 + k) * 256) * 4];
#pragma unroll
    for (int k = 0; k < 9; ++k)
      *(float4*)&pbase[(t + (half9 * 9 + k) * 256) * 4] = w[k];
    if (adst) {
#pragma unroll
      for (int k = 0; k < 9; ++k) {
        ushort4 o;
        o.x = f2b(w[k].x); o.y = f2b(w[k].y); o.z = f2b(w[k].z); o.w = f2b(w[k].w);
        *(ushort4*)&adst[(t + (half9 * 9 + k) * 256) * 4] = o;
      }
    }
  }
}

// -------- kernel 5 (fallback only): patches fp32 -> A bf16 (into dead xhwc) --------
__global__ __launch_bounds__(256) void k_cvt(const float* __restrict__ pat,
                                             u16* __restrict__ abf) {
  int e = (blockIdx.x * 256 + threadIdx.x) * 4;  // < 18,874,368
  float4 v = *(const float4*)(pat + e);
  ushort4 o;
  o.x = f2b(v.x); o.y = f2b(v.y); o.z = f2b(v.z); o.w = f2b(v.w);
  *(ushort4*)(abf + e) = o;
}

// -------- kernel 6: tokens = gelu(A @ proj_w^T + proj_b), fp32 out (round-9, UNCHANGED) ----
// M=8192 K=2304 N=768; BM=128 BN=64 BK=128 (18 K-steps, 48KB LDS, 3 blocks/CU);
// gload_lds w=16 + 16-slot XOR granule swizzle both sides; bijective XCD-chunk swizzle
// (768=8x96): one A-panel's 12 bn-blocks stay on one XCD's L2. K ascending in 32-chunks
// -> accumulation chain identical to the BK=32 original.
__global__ __launch_bounds__(256) void k_gemm(const u16* __restrict__ A,
                                              const u16* __restrict__ Bt,
                                              const float* __restrict__ pb,
                                              float* __restrict__ out) {
  __shared__ alignas(16) u16 As[128 * 128];  // 32KB
  __shared__ alignas(16) u16 Bs[64 * 128];   // 16KB
  const int bid = blockIdx.x;
  const int logical = (bid & 7) * 96 + (bid >> 3);   // XCD-contiguous chunks
  const int bn = logical % 12, bm = logical / 12;
  const int m0 = bm * 128, n0 = bn * 64;
  const int t = threadIdx.x, wv = t >> 6, l = t & 63, quad = l >> 4, lm = l & 15;
  const int rl = l >> 4;                 // chunk-local row 0..3
  const int slot = l & 15;               // dest granule slot

  f32x4 acc[2][4];
#pragma unroll
  for (int s = 0; s < 2; ++s)
#pragma unroll
    for (int u = 0; u < 4; ++u) acc[s][u] = (f32x4){0.f, 0.f, 0.f, 0.f};

  for (int k0 = 0; k0 < KP; k0 += 128) {
    __syncthreads();
    // 48 chunks of 1KB (As 32 + Bs 16); chunk = 4 rows x 256B; wave-uniform dests.
    for (int c = wv; c < 48; c += 4) {
      if (c < 32) {
        const int row = c * 4 + rl;
        const int gsw2 = slot ^ (row & 15);          // pre-swizzled source granule
        gload16(A + (size_t)(m0 + row) * KP + k0 + gsw2 * 8, As + c * 512);
      } else {
        const int row = (c - 32) * 4 + rl;
        const int gsw2 = slot ^ (row & 15);
        gload16(Bt + (size_t)(n0 + row) * KP + k0 + gsw2 * 8, Bs + (c - 32) * 512);
      }
    }
    __syncthreads();                     // vmcnt(0) drain
#pragma unroll
    for (int ks = 0; ks < 4; ++ks) {
      const int gx = ((ks * 4 + quad) ^ lm) << 3;    // row&15 == lm for all reads
      const bf16x8 a0 = *(const bf16x8*)&As[(wv * 32 + lm) * 128 + gx];
      const bf16x8 a1 = *(const bf16x8*)&As[(wv * 32 + 16 + lm) * 128 + gx];
#pragma unroll
      for (int u = 0; u < 4; ++u) {
        const bf16x8 b = *(const bf16x8*)&Bs[(u * 16 + lm) * 128 + gx];
        acc[0][u] = __builtin_amdgcn_mfma_f32_16x16x32_bf16(a0, b, acc[0][u], 0, 0, 0);
        acc[1][u] = __builtin_amdgcn_mfma_f32_16x16x32_bf16(a1, b, acc[1][u], 0, 0, 0);
      }
    }
  }
#pragma unroll
  for (int u = 0; u < 4; ++u) {
    const int n = n0 + u * 16 + lm;
    const float bias = pb[n];
#pragma unroll
    for (int s = 0; s < 2; ++s) {
#pragma unroll
      for (int rg = 0; rg < 4; ++rg) {
        const int m = m0 + wv * 32 + s * 16 + quad * 4 + rg;
        out[(size_t)m * DIMN + n] = gelu_f(acc[s][u][rg] + bias);
      }
    }
  }
}

extern "C" void kernel_launch(void* const* d_in, const int* in_sizes, int n_in,
                              void* d_out, int out_size, void* d_ws, size_t ws_size,
                              hipStream_t stream) {
  const float* x = (const float*)d_in[0];
  const float* conv_w = (const float*)d_in[1];
  const float* conv_b = (const float*)d_in[2];
  const float* bn_gamma = (const float*)d_in[3];
  const float* bn_beta = (const float*)d_in[4];
  const float* bn_mean = (const float*)d_in[5];
  const float* bn_var = (const float*)d_in[6];
  const float* proj_w = (const float*)d_in[7];
  const float* proj_b = (const float*)d_in[8];
  const float* mask = (const float*)d_in[9];
  float* out = (float*)d_out;         // [tokens][patches], fp32
  float* patches = out + TOKN;
  u16* ws = (u16*)d_ws;
  u16* xhwc = ws;
  u16* bp = ws + BP_OFF;
  u16* pw = ws + PW_OFF;

  const bool fused = ws_size >= WS_NEED_FUSED;
  u16* abf = fused ? ws + ABF_OFF : (u16*)nullptr;

  k_transpose<<<NFRM * HW, 256, 0, stream>>>(x, xhwc);   // halo zeroing fused in
  k_prep<<<1872, 256, 0, stream>>>(conv_w, proj_w, bp, pw);
  k_conv<<<NFRM * 32, 256, 0, stream>>>(xhwc, bp, conv_b, bn_gamma, bn_beta,
                                        bn_mean, bn_var, mask, patches, abf);
  if (!fused) {
    k_cvt<<<18432, 256, 0, stream>>>(patches, xhwc);  // xhwc dead after k_conv
    abf = xhwc;
  }
  k_gemm<<<64 * 12, 256, 0, stream>>>(abf, pw, proj_b, out);
}

// Round 13
// 293.630 us; speedup vs baseline: 1.0721x; 1.0097x over previous
//
#include <hip/hip_runtime.h>
#include <hip/hip_bf16.h>
#include <math.h>

// ImageTokenization: conv3x3(64->64)+BN+GELU -> patches(masked) -> proj GEMM(2304->768)+GELU
// Inputs fp32, outputs fp32; compute in bf16 MFMA (tolerance 8*2^-8).
// d_out (fp32) = [tokens 8192x768][patches 8192x2304].

typedef unsigned short u16;
typedef __bf16 bf16x8 __attribute__((ext_vector_type(8)));
typedef float f32x4 __attribute__((ext_vector_type(4)));

#define NFRM 32
#define CH 64
#define HW 96
#define HWP 98
#define KP 2304
#define DIMN 768
#define MTOK 8192
#define TOKN (MTOK * DIMN)          // 6,291,456 floats
#define NPAT (MTOK * KP)            // 18,874,368 floats
// ws layout (u16 units): [xhwc | bp | pw | abf(optional, ws-size-checked)]
#define XHWC_ELEMS ((size_t)NFRM * HWP * HWP * CH)   // 19,668,992
#define BP_OFF XHWC_ELEMS
#define PW_OFF (BP_OFF + 36864)
#define ABF_OFF (PW_OFF + 1769472)                   // 21,475,328
#define WS_NEED_FUSED (((size_t)ABF_OFF + (size_t)NPAT) * 2)  // bytes
#define BSTR 200                    // B LDS row stride (u16): 192 data + 8 pad

static __device__ __forceinline__ u16 f2b(float f) {
  unsigned u = __builtin_bit_cast(unsigned, f);
  u += 0x7fffu + ((u >> 16) & 1u);
  return (u16)(u >> 16);
}
static __device__ __forceinline__ float gelu_f(float x) {
  return 0.5f * x * (1.0f + erff(x * 0.7071067811865476f));
}

typedef __attribute__((address_space(3))) unsigned int lds_uint;
typedef __attribute__((address_space(1))) const unsigned int g_uint;
static __device__ __forceinline__ void gload16(const u16* g, u16* s) {
  // wave-uniform LDS base; HW writes base + lane*16; global src is per-lane.
  __builtin_amdgcn_global_load_lds((g_uint*)g, (lds_uint*)s, 16, 0, 0);
}

// -------- kernel 1: transpose + weight prep, FUSED (r13: one less launch gap) ----
// blocks 0..3071: x[32][64][96][96] fp32 -> xhwc[32][98][98][64] bf16 + halo zeroing
// blocks 3072..3215: conv_w[co][ci][3][3] fp32 -> bp[co][tap*64+ci] bf16
// blocks 3216..4943: proj_w fp32 -> pw bf16 (x4 vectorized)
// Prep blocks branch off before the barrier (block-uniform divergence, safe).
__global__ __launch_bounds__(256) void k_transpose(
    const float* __restrict__ x, u16* __restrict__ xhwc,
    const float* __restrict__ cw, const float* __restrict__ pwsrc,
    u16* __restrict__ bp, u16* __restrict__ pwd) {
  __shared__ u16 tile[96 * 66];  // [w][ci], stride 66 breaks bank collisions
  const int bb = blockIdx.x;
  if (bb >= NFRM * HW) {               // ---- weight-prep blocks ----
    const int b = bb - NFRM * HW;
    if (b < 144) {
      int e = b * 256 + threadIdx.x;   // < 36864
      int co = e / 576, r = e - co * 576, tap = r >> 6, ci = r & 63;
      bp[e] = f2b(cw[(co * 64 + ci) * 9 + tap]);
    } else {
      int e = ((b - 144) * 256 + threadIdx.x) * 4;  // < 1,769,472
      float4 v = *(const float4*)(pwsrc + e);
      ushort4 o;
      o.x = f2b(v.x); o.y = f2b(v.y); o.z = f2b(v.z); o.w = f2b(v.w);
      *(ushort4*)(pwd + e) = o;
    }
    return;
  }
  // ---- transpose blocks ----
  const int f = bb / 96, h = bb % 96;
  const int t = threadIdx.x;
  const float* xp = x + (size_t)f * CH * HW * HW + (size_t)h * HW;
#pragma unroll
  for (int k = 0; k < 6; ++k) {
    int e = (k * 256 + t) * 4;
    int ci = e / 96, w = e % 96;
    float4 v = *(const float4*)(xp + (size_t)ci * (HW * HW) + w);
    tile[(w + 0) * 66 + ci] = f2b(v.x);
    tile[(w + 1) * 66 + ci] = f2b(v.y);
    tile[(w + 2) * 66 + ci] = f2b(v.z);
    tile[(w + 3) * 66 + ci] = f2b(v.w);
  }
  __syncthreads();
  u16* frm = xhwc + (size_t)f * HWP * HWP * CH;
  u16* op = frm + ((size_t)(h + 1) * HWP + 1) * CH;
#pragma unroll
  for (int k = 0; k < 12; ++k) {
    int e2 = (k * 256 + t) * 2;
    int w = e2 >> 6, ci = e2 & 63;
    *(unsigned*)(op + e2) = *(const unsigned*)(&tile[w * 66 + ci]);
  }
  // ---- halo zeroing (fused, r10) ----
  const uint4 z = (uint4){0, 0, 0, 0};
  if (t < 16) {                          // col 0 and col 97 of row h+1
    const int col = (t < 8) ? 0 : 97;
    const int g = t & 7;
    *(uint4*)&frm[((size_t)(h + 1) * HWP + col) * CH + g * 8] = z;
  }
  if (h == 0) {                          // row 0: 98 px x 64 ch = 784 uint4
    for (int i = t; i < 784; i += 256) *(uint4*)&frm[(size_t)i * 8] = z;
  }
  if (h == 95) {                         // row 97
    u16* r97 = frm + (size_t)97 * HWP * CH;
    for (int i = t; i < 784; i += 256) *(uint4*)&r97[(size_t)i * 8] = z;
  }
}

// -------- kernel 4: half-strip conv (r9/6 structure; r12 single-Fsm-read epilogue). ----
// Block = frame x 8 patches (6 rows x 48 cols), 256 threads (4 waves = 2wm x 2wn).
// LOCAL OPTIMUM — all five structural variants lost: 512t/8w-grid-wide (r1), B-in-reg
// 3blk/CU (r4/r7: L2 thrash, FETCH 26.5->78-128MB), 8w co-split (r8: 2x A-LDS-reads),
// 6w pixel-split (r10: uneven SIMD mapping, occupancy DOWN). Also: no XCD swizzle (r4
// breaks producer->consumer L2 locality); store loops must stay branch-free (r5).
// A: 51,200B staged once (gload_lds w=16, granule-swizzled); B in LDS, 3-tap phases.
// Accumulation chain BIT-IDENTICAL to rounds 0-12.
__global__ __launch_bounds__(256, 2) void k_conv(
    const u16* __restrict__ xhwc, const u16* __restrict__ bw,
    const float* __restrict__ cb, const float* __restrict__ gma,
    const float* __restrict__ bta, const float* __restrict__ mu,
    const float* __restrict__ var, const float* __restrict__ msk,
    float* __restrict__ pout, u16* __restrict__ abf) {
  __shared__ alignas(16) char SMEM[76800];
  u16* Asm = (u16*)SMEM;                 // [400 px][64 u16], granule-swizzled
  u16* Bsm = (u16*)(SMEM + 51200);       // [64 co][BSTR u16], 3 taps per phase
  float* Fsm = (float*)SMEM;             // epilogue: 18,432 floats (73,728B)

  const int bx = blockIdx.x;
  const int f = bx >> 5, rem = bx & 31, pr = rem >> 1, half = rem & 1;
  const int t = threadIdx.x, wv = t >> 6, l = t & 63, quad = l >> 4, lm = l & 15;
  const int wm = wv >> 1, wn = wv & 1;

  // ---- stage A once: xhwc rows pr*6 .. +7, cols half*48 .. +49 (halo included) ----
  const u16* sbase = xhwc + (((size_t)f * HWP + pr * 6) * HWP + half * 48) * CH;
  const int pc = l >> 3;                 // pixel-in-chunk 0..7  (== p&7)
  const int gsw = (l & 7) ^ pc;          // source granule for dest slot (l&7)
  for (int c = wv; c < 50; c += 4) {
    const int p = c * 8 + pc;            // strip pixel 0..399
    const int row = p / 50, ac = p - row * 50;
    gload16(sbase + ((size_t)row * HWP + ac) * CH + gsw * 8, Asm + c * 512);
  }

  int pb[9];
#pragma unroll
  for (int mf = 0; mf < 9; ++mf) {       // per-frag pixel base (strip = [6 rows][48 cols])
    const int i16 = wm * 9 + mf;         // 16-px run; 3 runs per row
    pb[mf] = (i16 / 3) * 50 + (i16 % 3) * 16 + lm;
  }
  f32x4 acc[9][2];
#pragma unroll
  for (int mf = 0; mf < 9; ++mf) {
    acc[mf][0] = (f32x4){0.f, 0.f, 0.f, 0.f};
    acc[mf][1] = (f32x4){0.f, 0.f, 0.f, 0.f};
  }

  // ---- 3 phases: taps {0,1,2},{3,4,5},{6,7,8}; di = ph, dj = tp ----
#pragma unroll
  for (int ph = 0; ph < 3; ++ph) {
    if (ph > 0) __syncthreads();         // all Bsm reads of previous phase done
    for (int e = t; e < 1536; e += 256) {
      const int co = e / 24, kk = e - co * 24;
      *(uint4*)&Bsm[co * BSTR + kk * 8] =
          *(const uint4*)&bw[co * 576 + ph * 192 + kk * 8];
    }
    __syncthreads();                     // B ready (ph 0: also drains A gload_lds vmcnt)
#pragma unroll
    for (int tp = 0; tp < 3; ++tp) {
      const int di = ph, dj = tp;        // tap = 3*ph + tp
#pragma unroll
      for (int ks = 0; ks < 2; ++ks) {
        const int kq = ks * 4 + quad;
        const bf16x8 b0 = *(const bf16x8*)&Bsm[(wn * 32 + lm) * BSTR + tp * 64 + ks * 32 + quad * 8];
        const bf16x8 b1 = *(const bf16x8*)&Bsm[(wn * 32 + 16 + lm) * BSTR + tp * 64 + ks * 32 + quad * 8];
#pragma unroll
        for (int mf = 0; mf < 9; ++mf) {
          const int p = pb[mf] + di * 50 + dj;
          const bf16x8 a = *(const bf16x8*)&Asm[p * 64 + ((kq ^ (p & 7)) << 3)];
          acc[mf][0] = __builtin_amdgcn_mfma_f32_16x16x32_bf16(a, b0, acc[mf][0], 0, 0, 0);
          acc[mf][1] = __builtin_amdgcn_mfma_f32_16x16x32_bf16(a, b1, acc[mf][1], 0, 0, 0);
        }
      }
    }
  }

  // ---- epilogue: BN + GELU + mask -> LDS (pout layout) -> coalesced stores ----
  __syncthreads();                       // all Asm/Bsm reads done; reuse LDS as float buffer
#pragma unroll
  for (int nf = 0; nf < 2; ++nf) {
    const int co = wn * 32 + nf * 16 + lm;   // C/D col = lane&15
    const float scv = gma[co] * rsqrtf(var[co] + 1e-5f);
    const float b2v = (cb[co] - mu[co]) * scv + bta[co];
#pragma unroll
    for (int mf = 0; mf < 9; ++mf) {
#pragma unroll
      for (int rg = 0; rg < 4; ++rg) {
        const int sp = wm * 144 + mf * 16 + quad * 4 + rg;  // strip pixel (row = quad*4+rg)
        const int orow = sp / 48, oc = sp - orow * 48;
        const int nl = oc / 6, pj = oc - nl * 6;
        const int jj = orow * 6 + pj;
        float v = acc[mf][nf][rg] * scv + b2v;
        v = gelu_f(v) * msk[jj];
        Fsm[nl * 2304 + co * 36 + jj] = v;
      }
    }
  }
  __syncthreads();
  const size_t brow = (size_t)(f * 256 + pr * 16 + half * 8) * KP;
  float* pbase = pout + brow;
  u16* adst = abf ? abf + brow : (u16*)nullptr;
  // single Fsm read -> registers -> two batched branch-free store streams
#pragma unroll
  for (int half9 = 0; half9 < 2; ++half9) {
    float4 w[9];
#pragma unroll
    for (int k = 0; k < 9; ++k)
      w[k] = *(const float4*)&Fsm[(t + (half9 * 9 + k) * 256) * 4];
#pragma unroll
    for (int k = 0; k < 9; ++k)
      *(float4*)&pbase[(t + (half9 * 9 + k) * 256) * 4] = w[k];
    if (adst) {
#pragma unroll
      for (int k = 0; k < 9; ++k) {
        ushort4 o;
        o.x = f2b(w[k].x); o.y = f2b(w[k].y); o.z = f2b(w[k].z); o.w = f2b(w[k].w);
        *(ushort4*)&adst[(t + (half9 * 9 + k) * 256) * 4] = o;
      }
    }
  }
}

// -------- kernel 5 (fallback only): patches fp32 -> A bf16 (into dead xhwc) --------
__global__ __launch_bounds__(256) void k_cvt(const float* __restrict__ pat,
                                             u16* __restrict__ abf) {
  int e = (blockIdx.x * 256 + threadIdx.x) * 4;  // < 18,874,368
  float4 v = *(const float4*)(pat + e);
  ushort4 o;
  o.x = f2b(v.x); o.y = f2b(v.y); o.z = f2b(v.z); o.w = f2b(v.w);
  *(ushort4*)(abf + e) = o;
}

// -------- kernel 6: tokens = gelu(A @ proj_w^T + proj_b), fp32 out (round-9, UNCHANGED) ----
// M=8192 K=2304 N=768; BM=128 BN=64 BK=128 (18 K-steps, 48KB LDS, 3 blocks/CU);
// gload_lds w=16 + 16-slot XOR granule swizzle both sides; bijective XCD-chunk swizzle
// (768=8x96): one A-panel's 12 bn-blocks stay on one XCD's L2. K ascending in 32-chunks
// -> accumulation chain identical to the BK=32 original.
__global__ __launch_bounds__(256) void k_gemm(const u16* __restrict__ A,
                                              const u16* __restrict__ Bt,
                                              const float* __restrict__ pb,
                                              float* __restrict__ out) {
  __shared__ alignas(16) u16 As[128 * 128];  // 32KB
  __shared__ alignas(16) u16 Bs[64 * 128];   // 16KB
  const int bid = blockIdx.x;
  const int logical = (bid & 7) * 96 + (bid >> 3);   // XCD-contiguous chunks
  const int bn = logical % 12, bm = logical / 12;
  const int m0 = bm * 128, n0 = bn * 64;
  const int t = threadIdx.x, wv = t >> 6, l = t & 63, quad = l >> 4, lm = l & 15;
  const int rl = l >> 4;                 // chunk-local row 0..3
  const int slot = l & 15;               // dest granule slot

  f32x4 acc[2][4];
#pragma unroll
  for (int s = 0; s < 2; ++s)
#pragma unroll
    for (int u = 0; u < 4; ++u) acc[s][u] = (f32x4){0.f, 0.f, 0.f, 0.f};

  for (int k0 = 0; k0 < KP; k0 += 128) {
    __syncthreads();
    // 48 chunks of 1KB (As 32 + Bs 16); chunk = 4 rows x 256B; wave-uniform dests.
    for (int c = wv; c < 48; c += 4) {
      if (c < 32) {
        const int row = c * 4 + rl;
        const int gsw2 = slot ^ (row & 15);          // pre-swizzled source granule
        gload16(A + (size_t)(m0 + row) * KP + k0 + gsw2 * 8, As + c * 512);
      } else {
        const int row = (c - 32) * 4 + rl;
        const int gsw2 = slot ^ (row & 15);
        gload16(Bt + (size_t)(n0 + row) * KP + k0 + gsw2 * 8, Bs + (c - 32) * 512);
      }
    }
    __syncthreads();                     // vmcnt(0) drain
#pragma unroll
    for (int ks = 0; ks < 4; ++ks) {
      const int gx = ((ks * 4 + quad) ^ lm) << 3;    // row&15 == lm for all reads
      const bf16x8 a0 = *(const bf16x8*)&As[(wv * 32 + lm) * 128 + gx];
      const bf16x8 a1 = *(const bf16x8*)&As[(wv * 32 + 16 + lm) * 128 + gx];
#pragma unroll
      for (int u = 0; u < 4; ++u) {
        const bf16x8 b = *(const bf16x8*)&Bs[(u * 16 + lm) * 128 + gx];
        acc[0][u] = __builtin_amdgcn_mfma_f32_16x16x32_bf16(a0, b, acc[0][u], 0, 0, 0);
        acc[1][u] = __builtin_amdgcn_mfma_f32_16x16x32_bf16(a1, b, acc[1][u], 0, 0, 0);
      }
    }
  }
#pragma unroll
  for (int u = 0; u < 4; ++u) {
    const int n = n0 + u * 16 + lm;
    const float bias = pb[n];
#pragma unroll
    for (int s = 0; s < 2; ++s) {
#pragma unroll
      for (int rg = 0; rg < 4; ++rg) {
        const int m = m0 + wv * 32 + s * 16 + quad * 4 + rg;
        out[(size_t)m * DIMN + n] = gelu_f(acc[s][u][rg] + bias);
      }
    }
  }
}

extern "C" void kernel_launch(void* const* d_in, const int* in_sizes, int n_in,
                              void* d_out, int out_size, void* d_ws, size_t ws_size,
                              hipStream_t stream) {
  const float* x = (const float*)d_in[0];
  const float* conv_w = (const float*)d_in[1];
  const float* conv_b = (const float*)d_in[2];
  const float* bn_gamma = (const float*)d_in[3];
  const float* bn_beta = (const float*)d_in[4];
  const float* bn_mean = (const float*)d_in[5];
  const float* bn_var = (const float*)d_in[6];
  const float* proj_w = (const float*)d_in[7];
  const float* proj_b = (const float*)d_in[8];
  const float* mask = (const float*)d_in[9];
  float* out = (float*)d_out;         // [tokens][patches], fp32
  float* patches = out + TOKN;
  u16* ws = (u16*)d_ws;
  u16* xhwc = ws;
  u16* bp = ws + BP_OFF;
  u16* pw = ws + PW_OFF;

  const bool fused = ws_size >= WS_NEED_FUSED;
  u16* abf = fused ? ws + ABF_OFF : (u16*)nullptr;

  // transpose (3072 blocks) + halo zeroing + weight prep (1872 blocks), one launch
  k_transpose<<<NFRM * HW + 1872, 256, 0, stream>>>(x, xhwc, conv_w, proj_w, bp, pw);
  k_conv<<<NFRM * 32, 256, 0, stream>>>(xhwc, bp, conv_b, bn_gamma, bn_beta,
                                        bn_mean, bn_var, mask, patches, abf);
  if (!fused) {
    k_cvt<<<18432, 256, 0, stream>>>(patches, xhwc);  // xhwc dead after k_conv
    abf = xhwc;
  }
  k_gemm<<<64 * 12, 256, 0, stream>>>(abf, pw, proj_b, out);
}